// Round 5
// baseline (655.170 us; speedup 1.0000x reference)
//
#include <hip/hip_runtime.h>
#include <hip/hip_bf16.h>

typedef unsigned short u16;
typedef unsigned char  u8;
typedef unsigned int   u32;
typedef long long      i64;
using f32x4 = __attribute__((ext_vector_type(4))) float;
using i32x8 = __attribute__((ext_vector_type(8))) int;

#define EPSF 2.220446049250313e-16f
#define NS 4096      // samples
#define KP 6656      // padded K bytes: 128 ch * 52 (49 real + 3 zero-pad)
#define FSCALE 32.0f

#define GPTR(p) ((const __attribute__((address_space(1))) void*)(p))
#define LPTR(p) ((__attribute__((address_space(3))) void*)(p))

union frag8 { i32x8 v; i64 q[4]; };

// ---------------- indices + histogram + tile buckets ----------------
__global__ void k_idx(const float* __restrict__ tfld, const float* __restrict__ rfld,
                      int* __restrict__ idx, int* __restrict__ H,
                      int* __restrict__ cntT, int* __restrict__ bktT,
                      int* __restrict__ cntR, int* __restrict__ bktR){
  int t = blockIdx.x * 256 + threadIdx.x;
  if (t >= 2 * NS) return;
  const float* f = (t < NS) ? tfld : rfld;
  int s = t & (NS - 1);
  int base = (t < NS) ? 0 : 2 * NS;
  float gx = (f[2*s]   + 1.0f) * 0.5f * 83.0f;
  float gy = (f[2*s+1] + 1.0f) * 0.5f * 83.0f;
  int ix = (int)fminf(fmaxf(rintf(gx), 0.0f), 83.0f);
  int iy = (int)fminf(fmaxf(rintf(gy), 0.0f), 83.0f);
  idx[base + s]      = ix;
  idx[base + NS + s] = iy;
  int tile = (iy / 28) * 3 + (ix / 28);
  if (t < NS){
    int e = atomicAdd(&cntT[tile], 1);
    bktT[tile * 4096 + e] = s;
  } else {
    atomicAdd(&H[iy * 84 + ix], 1);
    int e = atomicAdd(&cntR[tile], 1);
    bktR[tile * 4096 + e] = s;
  }
}

// ---------------- per-channel mean, split into 3 row-bands ----------------
// ymean3[(c*3+band)*49 + k] = partial sum over band's positions
__global__ __launch_bounds__(256) void k_mean2(const float* __restrict__ refer,
                                               const int* __restrict__ H,
                                               float* __restrict__ ymean3){
  __shared__ int   Hs[28 * 84];
  __shared__ float part[4][49];
  int c = blockIdx.x, band = blockIdx.y;
  const float* plane = refer + ((size_t)c << 16);
  int ybase = band * 28;
  for (int p = threadIdx.x; p < 2352; p += 256) Hs[p] = H[ybase * 84 + p];
  __syncthreads();
  float acc[49];
  #pragma unroll
  for (int k = 0; k < 49; ++k) acc[k] = 0.f;
  for (int e = threadIdx.x; e < 2352; e += 256){
    int w = Hs[e];
    if (w){
      int y0 = ybase + e / 84, x0 = e % 84;
      float fw = (float)w;
      const float* pp = plane + (y0 * 3) * 256 + x0 * 3;
      #pragma unroll
      for (int ki = 0; ki < 7; ++ki)
        #pragma unroll
        for (int kj = 0; kj < 7; ++kj)
          acc[ki * 7 + kj] += fw * pp[ki * 256 + kj];
    }
  }
  int lane = threadIdx.x & 63, wid = threadIdx.x >> 6;
  #pragma unroll
  for (int k = 0; k < 49; ++k){
    float v = acc[k];
    #pragma unroll
    for (int o = 32; o > 0; o >>= 1) v += __shfl_down(v, o);
    if (lane == 0) part[wid][k] = v;
  }
  __syncthreads();
  for (int k = threadIdx.x; k < 49; k += 256)
    ymean3[(c * 3 + band) * 49 + k] =
      (part[0][k] + part[1][k] + part[2][k] + part[3][k]) * (1.0f / 4096.0f);
}

// ---------------- bucketed gather -> fp8 X (dword stores, swizzle-permuted) ----------------
// X row s: 1664 dwords; logical dword w stored at slot w ^ (2*(s&1)).
// channel c owns logical dwords c*13 .. c*13+12 (49 fp8 bytes * FSCALE + 3 zero pad)
__global__ __launch_bounds__(256) void k_gather(const float* __restrict__ feat,
                                                const int* __restrict__ ixv,
                                                const int* __restrict__ iyv,
                                                const int* __restrict__ cnt,
                                                const int* __restrict__ bkt,
                                                const float* __restrict__ ymean3,
                                                u8* __restrict__ X,
                                                float* __restrict__ nsq){
  __shared__ float R[88 * 92];
  __shared__ float ms[49];
  int c = blockIdx.x;      // 0..127
  int t = blockIdx.y;      // 0..8
  int ty = t / 3, tx = t % 3;
  const float* src = feat + ((size_t)c << 16) + (ty * 84) * 256 + tx * 84;
  for (int e = threadIdx.x; e < 88 * 22; e += 256){
    int r = e / 22, q = e % 22;
    *(f32x4*)&R[r * 92 + q * 4] = *(const f32x4*)(src + r * 256 + q * 4);
  }
  for (int k = threadIdx.x; k < 49; k += 256)
    ms[k] = ymean3[(c*3)*49 + k] + ymean3[(c*3+1)*49 + k] + ymean3[(c*3+2)*49 + k];
  __syncthreads();
  int n = cnt[t];
  const int* list = bkt + t * 4096;
  for (int e = threadIdx.x; e < n; e += 256){
    int s = list[e];
    int ly = iyv[s] * 3 - ty * 84;
    int lx = ixv[s] * 3 - tx * 84;
    u32* xr = (u32*)(X + (size_t)s * KP);
    int wbase = c * 13;
    int sw = (s & 1) << 1;
    float ss = 0.f;
    #pragma unroll
    for (int d = 0; d < 12; ++d){
      float v0 = R[(ly + (4*d+0)/7) * 92 + lx + (4*d+0)%7] - ms[4*d+0];
      float v1 = R[(ly + (4*d+1)/7) * 92 + lx + (4*d+1)%7] - ms[4*d+1];
      float v2 = R[(ly + (4*d+2)/7) * 92 + lx + (4*d+2)%7] - ms[4*d+2];
      float v3 = R[(ly + (4*d+3)/7) * 92 + lx + (4*d+3)%7] - ms[4*d+3];
      ss += v0*v0 + v1*v1 + v2*v2 + v3*v3;
      u32 dw = (u32)__builtin_amdgcn_cvt_pk_fp8_f32(v0 * FSCALE, v1 * FSCALE, 0, false);
      dw = (u32)__builtin_amdgcn_cvt_pk_fp8_f32(v2 * FSCALE, v3 * FSCALE, (int)dw, true);
      xr[(wbase + d) ^ sw] = dw;
    }
    float v = R[(ly + 6) * 92 + lx + 6] - ms[48];
    ss += v * v;
    xr[(wbase + 12) ^ sw] = (u32)__builtin_amdgcn_cvt_pk_fp8_f32(v * FSCALE, 0.0f, 0, false);
    atomicAdd(&nsq[s], ss);
  }
}

// ---------------- reciprocal norms (1/FSCALE folded in) ----------------
__global__ void k_rnorm(const float* __restrict__ nsq, float* __restrict__ rn){
  int i = blockIdx.x * 256 + threadIdx.x;
  if (i < 2 * NS) rn[i] = (1.0f / FSCALE) / (sqrtf(nsq[i]) + EPSF);
}

// ---------------- mask patch gather (k-major, fp32) + squared norms ----------------
__global__ void k_maskg(const float* __restrict__ mask,
                        const int* __restrict__ ixv, const int* __restrict__ iyv,
                        float* __restrict__ P, float* __restrict__ nsq){
  int s = blockIdx.x * 256 + threadIdx.x;
  if (s >= NS) return;
  int bx = ixv[s] * 3, by = iyv[s] * 3;
  float ss = 0.f;
  #pragma unroll
  for (int ki = 0; ki < 7; ++ki){
    #pragma unroll
    for (int kj = 0; kj < 7; ++kj){
      float v = mask[(by + ki) * 256 + (bx + kj)];
      P[(ki * 7 + kj) * NS + s] = v;
      ss += v * v;
    }
  }
  nsq[s] = ss;
}

// ---------------- d_prog: D[i][j] = (10/49)*max(0, nrp[j]+ntp[i]-2*tp_j.rp_i) ----------------
__global__ __launch_bounds__(256) void k_dprog(const float* __restrict__ TP,
                                               const float* __restrict__ RP,
                                               const float* __restrict__ ntp,
                                               const float* __restrict__ nrp,
                                               float* __restrict__ D){
  __shared__ float Ts[49][128];
  __shared__ float Rs[49][128];
  int j0 = blockIdx.x * 128, i0 = blockIdx.y * 128;
  for (int e = threadIdx.x; e < 49 * 128; e += 256){
    int k = e >> 7, s = e & 127;
    Ts[k][s] = TP[k * NS + j0 + s];
    Rs[k][s] = RP[k * NS + i0 + s];
  }
  __syncthreads();
  int tx = threadIdx.x & 15, ty = threadIdx.x >> 4;
  float acc[8][8] = {};
  for (int k = 0; k < 49; ++k){
    float ra[8], rb[8];
    #pragma unroll
    for (int a = 0; a < 8; ++a) ra[a] = Rs[k][ty * 8 + a];
    #pragma unroll
    for (int b = 0; b < 8; ++b) rb[b] = Ts[k][tx * 8 + b];
    #pragma unroll
    for (int a = 0; a < 8; ++a)
      #pragma unroll
      for (int b = 0; b < 8; ++b) acc[a][b] += ra[a] * rb[b];
  }
  #pragma unroll
  for (int a = 0; a < 8; ++a){
    int i = i0 + ty * 8 + a;
    float ni = ntp[i];
    #pragma unroll
    for (int b = 0; b < 8; ++b){
      int j = j0 + tx * 8 + b;
      float v = nrp[j] + ni - 2.0f * acc[a][b];
      D[(size_t)i * NS + j] = fmaxf(v, 0.0f) * (10.0f / 49.0f);
    }
  }
}

// ---------------- main GEMM (MX fp8, K=128 MFMA, scales=1.0) ----------------
// 128x128 tile, BK=128 bytes, 52 K-iters. LDS: logical 8-B block b of row r at
// block b^(r&15) (conflict-free frag reads). Staging XOR (r>>1)&7 on 16-B chunks;
// X pre-permuted (dword w -> w^(2*(r&1))) completes the swizzle.
__global__ __launch_bounds__(256, 4) void k_gemm(const u8* __restrict__ Xt,
                                                 const u8* __restrict__ Xr,
                                                 const float* __restrict__ rnt,
                                                 const float* __restrict__ rnr,
                                                 float* __restrict__ D){
  __shared__ u8 As[128 * 128];
  __shared__ u8 Bs[128 * 128];
  const int tid  = threadIdx.x;
  const int lane = tid & 63;
  const int w    = tid >> 6;
  const int wm   = w >> 1, wn = w & 1;
  const int b    = blockIdx.x;
  const int xcd  = b & 7, kb = b >> 3;
  const int i0 = ((xcd & 3) * 8 + (kb & 7)) * 128;
  const int j0 = ((xcd >> 2) * 16 + (kb >> 3)) * 128;

  // staging: wave w stages rows [w*32, w*32+32), 4 issues of 8 rows
  const int srow = lane >> 3;              // 0..7
  const int cs   = lane & 7;               // LDS 16-B chunk
  const int g0   = cs ^ (srow >> 1);       // global chunk, even issues
  const int g1   = g0 ^ 4;                 // odd issues
  const u8* gae = Xt + (size_t)(i0 + w * 32 + srow) * KP + g0 * 16;
  const u8* gao = Xt + (size_t)(i0 + w * 32 + srow) * KP + g1 * 16;
  const u8* gbe = Xr + (size_t)(j0 + w * 32 + srow) * KP + g0 * 16;
  const u8* gbo = Xr + (size_t)(j0 + w * 32 + srow) * KP + g1 * 16;
  u8* la = As + (w * 32) * 128;
  u8* lb = Bs + (w * 32) * 128;

  const int kg   = lane >> 4;              // 0..3 (K-group; also C/D row group)
  const int mrow = lane & 15;
  // frag b64 offsets: row*128 + ((kg*4+j)^mrow)*8 ; + t*2048 per 16-row tile
  int offA[4], offB[4];
  #pragma unroll
  for (int j = 0; j < 4; ++j){
    offA[j] = (wm * 64 + mrow) * 128 + (((kg * 4 + j) ^ mrow) * 8);
    offB[j] = (wn * 64 + mrow) * 128 + (((kg * 4 + j) ^ mrow) * 8);
  }

  f32x4 acc[4][4] = {};

  for (int kt = 0; kt < 52; ++kt){        // 52 * 128 = 6656
    #pragma unroll
    for (int ii = 0; ii < 4; ++ii){
      const u8* pa = (ii & 1) ? gao : gae;
      const u8* pb = (ii & 1) ? gbo : gbe;
      __builtin_amdgcn_global_load_lds(GPTR(pa + ii * 8 * KP), LPTR(la + ii * 1024), 16, 0, 0);
      __builtin_amdgcn_global_load_lds(GPTR(pb + ii * 8 * KP), LPTR(lb + ii * 1024), 16, 0, 0);
    }
    gae += 128; gao += 128; gbe += 128; gbo += 128;
    __syncthreads();

    frag8 bf[4];
    #pragma unroll
    for (int t = 0; t < 4; ++t)
      #pragma unroll
      for (int j = 0; j < 4; ++j)
        bf[t].q[j] = *(const i64*)(Bs + offB[j] + t * 2048);
    #pragma unroll
    for (int a = 0; a < 4; ++a){
      frag8 af;
      #pragma unroll
      for (int j = 0; j < 4; ++j)
        af.q[j] = *(const i64*)(As + offA[j] + a * 2048);
      #pragma unroll
      for (int bq = 0; bq < 4; ++bq)
        acc[a][bq] = __builtin_amdgcn_mfma_scale_f32_16x16x128_f8f6f4(
            af.v, bf[bq].v, acc[a][bq], 0, 0, 0, 127, 0, 127);
    }
    __syncthreads();
  }

  // epilogue: C/D layout col=lane&15 (j), row=kg*4+reg (i); rn carries 1/FSCALE
  #pragma unroll
  for (int bq = 0; bq < 4; ++bq){
    int j = j0 + wn * 64 + bq * 16 + mrow;
    float rj = rnr[j];
    #pragma unroll
    for (int a = 0; a < 4; ++a){
      #pragma unroll
      for (int r = 0; r < 4; ++r){
        int i = i0 + wm * 64 + a * 16 + kg * 4 + r;
        float sim  = acc[a][bq][r] * rnt[i] * rj;
        float dcos = fmaxf((1.0f - sim) * 0.5f, 0.0f);
        D[(size_t)i * NS + j] += dcos;
      }
    }
  }
}

// ---------------- per-row: min -> w=exp(2(1-d/dmin)) -> log(maxw/sumw) ----------------
__global__ __launch_bounds__(256) void k_rowred(const float* __restrict__ D,
                                                float* __restrict__ logcx){
  int i = blockIdx.x, tid = threadIdx.x;
  const float* row = D + (size_t)i * NS;
  float v[16];
  float mn = 3.4e38f;
  #pragma unroll
  for (int t = 0; t < 16; ++t){ v[t] = row[tid + t * 256]; mn = fminf(mn, v[t]); }
  __shared__ float r1[256], r2[256];
  r1[tid] = mn; __syncthreads();
  for (int s2 = 128; s2 > 0; s2 >>= 1){
    if (tid < s2) r1[tid] = fminf(r1[tid], r1[tid + s2]);
    __syncthreads();
  }
  float inv = 1.0f / (r1[0] + EPSF);
  __syncthreads();
  float sw = 0.f, mw = 0.f;
  #pragma unroll
  for (int t = 0; t < 16; ++t){
    float wv = expf((1.0f - v[t] * inv) * 2.0f);
    sw += wv; mw = fmaxf(mw, wv);
  }
  r1[tid] = sw; r2[tid] = mw; __syncthreads();
  for (int s2 = 128; s2 > 0; s2 >>= 1){
    if (tid < s2){ r1[tid] += r1[tid + s2]; r2[tid] = fmaxf(r2[tid], r2[tid + s2]); }
    __syncthreads();
  }
  if (tid == 0) logcx[i] = logf(r2[0] / r1[0]);
}

__global__ void k_final(const float* __restrict__ logcx, float* __restrict__ out){
  int tid = threadIdx.x;
  float s = 0.f;
  for (int t = tid; t < NS; t += 256) s += logcx[t];
  __shared__ float r[256];
  r[tid] = s; __syncthreads();
  for (int k = 128; k > 0; k >>= 1){
    if (tid < k) r[tid] += r[tid + k];
    __syncthreads();
  }
  if (tid == 0) out[0] = -(r[0] * (1.0f / 4096.0f));
}

extern "C" void kernel_launch(void* const* d_in, const int* in_sizes, int n_in,
                              void* d_out, int out_size, void* d_ws, size_t ws_size,
                              hipStream_t stream){
  (void)in_sizes; (void)n_in; (void)out_size; (void)ws_size;
  const float* tfeat = (const float*)d_in[0];
  const float* rfeat = (const float*)d_in[1];
  const float* mask  = (const float*)d_in[2];
  const float* tfld  = (const float*)d_in[3];
  const float* rfld  = (const float*)d_in[4];

  char* p = (char*)d_ws;
  auto take = [&](size_t bytes) -> char* {
    char* r = p; p += (bytes + 255) & ~(size_t)255; return r;
  };
  int*   idx    = (int*)  take(4 * NS * sizeof(int));
  int*   H      = (int*)  take(7056 * sizeof(int));
  int*   cntT   = (int*)  take(9 * sizeof(int));
  int*   cntR   = (int*)  take(9 * sizeof(int));
  int*   bktT   = (int*)  take(9 * 4096 * sizeof(int));
  int*   bktR   = (int*)  take(9 * 4096 * sizeof(int));
  float* ymean3 = (float*)take(128 * 3 * 49 * sizeof(float));
  float* nsq    = (float*)take(2 * NS * sizeof(float));
  float* rn     = (float*)take(2 * NS * sizeof(float));
  float* ntp    = (float*)take(NS * sizeof(float));
  float* nrp    = (float*)take(NS * sizeof(float));
  float* TP     = (float*)take((size_t)49 * NS * sizeof(float));
  float* RP     = (float*)take((size_t)49 * NS * sizeof(float));
  u8*    Xt     = (u8*)   take((size_t)NS * KP);
  u8*    Xr     = (u8*)   take((size_t)NS * KP);
  float* D      = (float*)take((size_t)NS * NS * sizeof(float));
  float* lcx    = (float*)take(NS * sizeof(float));

  hipMemsetAsync(nsq, 0, 2 * NS * sizeof(float), stream);
  hipMemsetAsync(H, 0, 7056 * sizeof(int), stream);
  hipMemsetAsync(cntT, 0, 9 * sizeof(int), stream);
  hipMemsetAsync(cntR, 0, 9 * sizeof(int), stream);
  k_idx<<<32, 256, 0, stream>>>(tfld, rfld, idx, H, cntT, bktT, cntR, bktR);
  k_mean2<<<dim3(128, 3), 256, 0, stream>>>(rfeat, H, ymean3);
  k_gather<<<dim3(128, 9), 256, 0, stream>>>(tfeat, idx,          idx + NS,     cntT, bktT, ymean3, Xt, nsq);
  k_gather<<<dim3(128, 9), 256, 0, stream>>>(rfeat, idx + 2 * NS, idx + 3 * NS, cntR, bktR, ymean3, Xr, nsq + NS);
  k_rnorm<<<32, 256, 0, stream>>>(nsq, rn);
  k_maskg<<<16, 256, 0, stream>>>(mask, idx,          idx + NS,     TP, ntp);
  k_maskg<<<16, 256, 0, stream>>>(mask, idx + 2 * NS, idx + 3 * NS, RP, nrp);
  k_dprog<<<dim3(32, 32), 256, 0, stream>>>(TP, RP, ntp, nrp, D);
  k_gemm<<<1024, 256, 0, stream>>>(Xt, Xr, rn, rn + NS, D);
  k_rowred<<<4096, 256, 0, stream>>>(D, lcx);
  k_final<<<1, 256, 0, stream>>>(lcx, (float*)d_out);
}

// Round 6
// 490.565 us; speedup vs baseline: 1.3355x; 1.3355x over previous
//
#include <hip/hip_runtime.h>
#include <hip/hip_bf16.h>

typedef unsigned short u16;
typedef unsigned char  u8;
typedef unsigned int   u32;
typedef long long      i64;
using f32x4 = __attribute__((ext_vector_type(4))) float;
using i32x8 = __attribute__((ext_vector_type(8))) int;

#define EPSF 2.220446049250313e-16f
#define NS 4096      // samples
#define KP 6656      // padded K bytes: 128 ch * 52 (49 real + 3 zero-pad)
#define FSCALE 32.0f

#define GPTR(p) ((const __attribute__((address_space(1))) void*)(p))
#define LPTR(p) ((__attribute__((address_space(3))) void*)(p))

union frag8 { i32x8 v; i64 q[4]; };

// ---------------- indices + histogram + tile buckets ----------------
__global__ void k_idx(const float* __restrict__ tfld, const float* __restrict__ rfld,
                      int* __restrict__ idx, int* __restrict__ H,
                      int* __restrict__ cntT, int* __restrict__ bktT,
                      int* __restrict__ cntR, int* __restrict__ bktR){
  int t = blockIdx.x * 256 + threadIdx.x;
  if (t >= 2 * NS) return;
  const float* f = (t < NS) ? tfld : rfld;
  int s = t & (NS - 1);
  int base = (t < NS) ? 0 : 2 * NS;
  float gx = (f[2*s]   + 1.0f) * 0.5f * 83.0f;
  float gy = (f[2*s+1] + 1.0f) * 0.5f * 83.0f;
  int ix = (int)fminf(fmaxf(rintf(gx), 0.0f), 83.0f);
  int iy = (int)fminf(fmaxf(rintf(gy), 0.0f), 83.0f);
  idx[base + s]      = ix;
  idx[base + NS + s] = iy;
  int tile = (iy / 28) * 3 + (ix / 28);
  if (t < NS){
    int e = atomicAdd(&cntT[tile], 1);
    bktT[tile * 4096 + e] = s;
  } else {
    atomicAdd(&H[iy * 84 + ix], 1);
    int e = atomicAdd(&cntR[tile], 1);
    bktR[tile * 4096 + e] = s;
  }
}

// ---------------- per-channel mean, split into 3 row-bands ----------------
__global__ __launch_bounds__(256) void k_mean2(const float* __restrict__ refer,
                                               const int* __restrict__ H,
                                               float* __restrict__ ymean3){
  __shared__ int   Hs[28 * 84];
  __shared__ float part[4][49];
  int c = blockIdx.x, band = blockIdx.y;
  const float* plane = refer + ((size_t)c << 16);
  int ybase = band * 28;
  for (int p = threadIdx.x; p < 2352; p += 256) Hs[p] = H[ybase * 84 + p];
  __syncthreads();
  float acc[49];
  #pragma unroll
  for (int k = 0; k < 49; ++k) acc[k] = 0.f;
  for (int e = threadIdx.x; e < 2352; e += 256){
    int w = Hs[e];
    if (w){
      int y0 = ybase + e / 84, x0 = e % 84;
      float fw = (float)w;
      const float* pp = plane + (y0 * 3) * 256 + x0 * 3;
      #pragma unroll
      for (int ki = 0; ki < 7; ++ki)
        #pragma unroll
        for (int kj = 0; kj < 7; ++kj)
          acc[ki * 7 + kj] += fw * pp[ki * 256 + kj];
    }
  }
  int lane = threadIdx.x & 63, wid = threadIdx.x >> 6;
  #pragma unroll
  for (int k = 0; k < 49; ++k){
    float v = acc[k];
    #pragma unroll
    for (int o = 32; o > 0; o >>= 1) v += __shfl_down(v, o);
    if (lane == 0) part[wid][k] = v;
  }
  __syncthreads();
  for (int k = threadIdx.x; k < 49; k += 256)
    ymean3[(c * 3 + band) * 49 + k] =
      (part[0][k] + part[1][k] + part[2][k] + part[3][k]) * (1.0f / 4096.0f);
}

// ---------------- bucketed gather -> fp8 X (dword stores, swizzle-permuted) ----------------
// X row s: 1664 dwords; logical dword w stored at slot w ^ (2*(s&1)).
// channel c owns logical dwords c*13 .. c*13+12 (49 fp8 bytes * FSCALE + 3 zero pad)
__global__ __launch_bounds__(256) void k_gather(const float* __restrict__ feat,
                                                const int* __restrict__ ixv,
                                                const int* __restrict__ iyv,
                                                const int* __restrict__ cnt,
                                                const int* __restrict__ bkt,
                                                const float* __restrict__ ymean3,
                                                u8* __restrict__ X,
                                                float* __restrict__ nsq){
  __shared__ float R[88 * 92];
  __shared__ float ms[49];
  int c = blockIdx.x;      // 0..127
  int t = blockIdx.y;      // 0..8
  int ty = t / 3, tx = t % 3;
  const float* src = feat + ((size_t)c << 16) + (ty * 84) * 256 + tx * 84;
  for (int e = threadIdx.x; e < 88 * 22; e += 256){
    int r = e / 22, q = e % 22;
    *(f32x4*)&R[r * 92 + q * 4] = *(const f32x4*)(src + r * 256 + q * 4);
  }
  for (int k = threadIdx.x; k < 49; k += 256)
    ms[k] = ymean3[(c*3)*49 + k] + ymean3[(c*3+1)*49 + k] + ymean3[(c*3+2)*49 + k];
  __syncthreads();
  int n = cnt[t];
  const int* list = bkt + t * 4096;
  for (int e = threadIdx.x; e < n; e += 256){
    int s = list[e];
    int ly = iyv[s] * 3 - ty * 84;
    int lx = ixv[s] * 3 - tx * 84;
    u32* xr = (u32*)(X + (size_t)s * KP);
    int wbase = c * 13;
    int sw = (s & 1) << 1;
    float ss = 0.f;
    #pragma unroll
    for (int d = 0; d < 12; ++d){
      float v0 = R[(ly + (4*d+0)/7) * 92 + lx + (4*d+0)%7] - ms[4*d+0];
      float v1 = R[(ly + (4*d+1)/7) * 92 + lx + (4*d+1)%7] - ms[4*d+1];
      float v2 = R[(ly + (4*d+2)/7) * 92 + lx + (4*d+2)%7] - ms[4*d+2];
      float v3 = R[(ly + (4*d+3)/7) * 92 + lx + (4*d+3)%7] - ms[4*d+3];
      ss += v0*v0 + v1*v1 + v2*v2 + v3*v3;
      u32 dw = (u32)__builtin_amdgcn_cvt_pk_fp8_f32(v0 * FSCALE, v1 * FSCALE, 0, false);
      dw = (u32)__builtin_amdgcn_cvt_pk_fp8_f32(v2 * FSCALE, v3 * FSCALE, (int)dw, true);
      xr[(wbase + d) ^ sw] = dw;
    }
    float v = R[(ly + 6) * 92 + lx + 6] - ms[48];
    ss += v * v;
    xr[(wbase + 12) ^ sw] = (u32)__builtin_amdgcn_cvt_pk_fp8_f32(v * FSCALE, 0.0f, 0, false);
    atomicAdd(&nsq[s], ss);
  }
}

// ---------------- reciprocal norms (1/FSCALE folded in) ----------------
__global__ void k_rnorm(const float* __restrict__ nsq, float* __restrict__ rn){
  int i = blockIdx.x * 256 + threadIdx.x;
  if (i < 2 * NS) rn[i] = (1.0f / FSCALE) / (sqrtf(nsq[i]) + EPSF);
}

// ---------------- mask patch gather (k-major, fp32) + squared norms ----------------
__global__ void k_maskg(const float* __restrict__ mask,
                        const int* __restrict__ ixv, const int* __restrict__ iyv,
                        float* __restrict__ P, float* __restrict__ nsq){
  int s = blockIdx.x * 256 + threadIdx.x;
  if (s >= NS) return;
  int bx = ixv[s] * 3, by = iyv[s] * 3;
  float ss = 0.f;
  #pragma unroll
  for (int ki = 0; ki < 7; ++ki){
    #pragma unroll
    for (int kj = 0; kj < 7; ++kj){
      float v = mask[(by + ki) * 256 + (bx + kj)];
      P[(ki * 7 + kj) * NS + s] = v;
      ss += v * v;
    }
  }
  nsq[s] = ss;
}

// ---------------- d_prog: D[i][j] = (10/49)*max(0, nrp[j]+ntp[i]-2*tp_j.rp_i) ----------------
__global__ __launch_bounds__(256) void k_dprog(const float* __restrict__ TP,
                                               const float* __restrict__ RP,
                                               const float* __restrict__ ntp,
                                               const float* __restrict__ nrp,
                                               float* __restrict__ D){
  __shared__ float Ts[49][128];
  __shared__ float Rs[49][128];
  int j0 = blockIdx.x * 128, i0 = blockIdx.y * 128;
  for (int e = threadIdx.x; e < 49 * 128; e += 256){
    int k = e >> 7, s = e & 127;
    Ts[k][s] = TP[k * NS + j0 + s];
    Rs[k][s] = RP[k * NS + i0 + s];
  }
  __syncthreads();
  int tx = threadIdx.x & 15, ty = threadIdx.x >> 4;
  float acc[8][8] = {};
  for (int k = 0; k < 49; ++k){
    float ra[8], rb[8];
    #pragma unroll
    for (int a = 0; a < 8; ++a) ra[a] = Rs[k][ty * 8 + a];
    #pragma unroll
    for (int b = 0; b < 8; ++b) rb[b] = Ts[k][tx * 8 + b];
    #pragma unroll
    for (int a = 0; a < 8; ++a)
      #pragma unroll
      for (int b = 0; b < 8; ++b) acc[a][b] += ra[a] * rb[b];
  }
  #pragma unroll
  for (int a = 0; a < 8; ++a){
    int i = i0 + ty * 8 + a;
    float ni = ntp[i];
    #pragma unroll
    for (int b = 0; b < 8; ++b){
      int j = j0 + tx * 8 + b;
      float v = nrp[j] + ni - 2.0f * acc[a][b];
      D[(size_t)i * NS + j] = fmaxf(v, 0.0f) * (10.0f / 49.0f);
    }
  }
}

// ---------------- main GEMM (MX fp8, K=128 MFMA, scales=1.0) ----------------
// 128x128 tile, BK=128 bytes, 52 K-iters. LDS: logical 8-B block b of row r at
// block b^(r&15) (conflict-free frag reads). Staging XOR (r>>1)&7 on 16-B chunks;
// X pre-permuted (dword w -> w^(2*(r&1))) completes the swizzle.
// NOTE: no min-waves launch bound — (256,4) split the unified RF as 64 AGPR
// (acc) + 64 arch VGPR, overflowing the K-loop working set into scratch
// (WRITE_SIZE 820 MB, r5). Unconstrained allocation (~144 @ 3 blocks/CU) is
// the round-4-verified no-spill regime.
__global__ __launch_bounds__(256) void k_gemm(const u8* __restrict__ Xt,
                                              const u8* __restrict__ Xr,
                                              const float* __restrict__ rnt,
                                              const float* __restrict__ rnr,
                                              float* __restrict__ D){
  __shared__ u8 As[128 * 128];
  __shared__ u8 Bs[128 * 128];
  const int tid  = threadIdx.x;
  const int lane = tid & 63;
  const int w    = tid >> 6;
  const int wm   = w >> 1, wn = w & 1;
  const int b    = blockIdx.x;
  const int xcd  = b & 7, kb = b >> 3;
  const int i0 = ((xcd & 3) * 8 + (kb & 7)) * 128;
  const int j0 = ((xcd >> 2) * 16 + (kb >> 3)) * 128;

  // staging: wave w stages rows [w*32, w*32+32), 4 issues of 8 rows
  const int srow = lane >> 3;              // 0..7
  const int cs   = lane & 7;               // LDS 16-B chunk
  const int g0   = cs ^ (srow >> 1);       // global chunk, even issues
  const int g1   = g0 ^ 4;                 // odd issues
  const u8* gae = Xt + (size_t)(i0 + w * 32 + srow) * KP + g0 * 16;
  const u8* gao = Xt + (size_t)(i0 + w * 32 + srow) * KP + g1 * 16;
  const u8* gbe = Xr + (size_t)(j0 + w * 32 + srow) * KP + g0 * 16;
  const u8* gbo = Xr + (size_t)(j0 + w * 32 + srow) * KP + g1 * 16;
  u8* la = As + (w * 32) * 128;
  u8* lb = Bs + (w * 32) * 128;

  const int kg   = lane >> 4;              // 0..3 (K-group; also C/D row group)
  const int mrow = lane & 15;
  // frag b64 offsets: row*128 + ((kg*4+j)^mrow)*8 ; + t*2048 per 16-row tile
  int offA[4], offB[4];
  #pragma unroll
  for (int j = 0; j < 4; ++j){
    offA[j] = (wm * 64 + mrow) * 128 + (((kg * 4 + j) ^ mrow) * 8);
    offB[j] = (wn * 64 + mrow) * 128 + (((kg * 4 + j) ^ mrow) * 8);
  }

  f32x4 acc[4][4] = {};

  for (int kt = 0; kt < 52; ++kt){        // 52 * 128 = 6656
    #pragma unroll
    for (int ii = 0; ii < 4; ++ii){
      const u8* pa = (ii & 1) ? gao : gae;
      const u8* pb = (ii & 1) ? gbo : gbe;
      __builtin_amdgcn_global_load_lds(GPTR(pa + ii * 8 * KP), LPTR(la + ii * 1024), 16, 0, 0);
      __builtin_amdgcn_global_load_lds(GPTR(pb + ii * 8 * KP), LPTR(lb + ii * 1024), 16, 0, 0);
    }
    gae += 128; gao += 128; gbe += 128; gbo += 128;
    __syncthreads();

    frag8 bf[4];
    #pragma unroll
    for (int t = 0; t < 4; ++t)
      #pragma unroll
      for (int j = 0; j < 4; ++j)
        bf[t].q[j] = *(const i64*)(Bs + offB[j] + t * 2048);
    #pragma unroll
    for (int a = 0; a < 4; ++a){
      frag8 af;
      #pragma unroll
      for (int j = 0; j < 4; ++j)
        af.q[j] = *(const i64*)(As + offA[j] + a * 2048);
      #pragma unroll
      for (int bq = 0; bq < 4; ++bq)
        acc[a][bq] = __builtin_amdgcn_mfma_scale_f32_16x16x128_f8f6f4(
            af.v, bf[bq].v, acc[a][bq], 0, 0, 0, 127, 0, 127);
    }
    __syncthreads();
  }

  // epilogue: C/D layout col=lane&15 (j), row=kg*4+reg (i); rn carries 1/FSCALE
  #pragma unroll
  for (int bq = 0; bq < 4; ++bq){
    int j = j0 + wn * 64 + bq * 16 + mrow;
    float rj = rnr[j];
    #pragma unroll
    for (int a = 0; a < 4; ++a){
      #pragma unroll
      for (int r = 0; r < 4; ++r){
        int i = i0 + wm * 64 + a * 16 + kg * 4 + r;
        float sim  = acc[a][bq][r] * rnt[i] * rj;
        float dcos = fmaxf((1.0f - sim) * 0.5f, 0.0f);
        D[(size_t)i * NS + j] += dcos;
      }
    }
  }
}

// ---------------- per-row: min -> w=exp(2(1-d/dmin)) -> log(maxw/sumw) ----------------
__global__ __launch_bounds__(256) void k_rowred(const float* __restrict__ D,
                                                float* __restrict__ logcx){
  int i = blockIdx.x, tid = threadIdx.x;
  const float* row = D + (size_t)i * NS;
  float v[16];
  float mn = 3.4e38f;
  #pragma unroll
  for (int t = 0; t < 16; ++t){ v[t] = row[tid + t * 256]; mn = fminf(mn, v[t]); }
  __shared__ float r1[256], r2[256];
  r1[tid] = mn; __syncthreads();
  for (int s2 = 128; s2 > 0; s2 >>= 1){
    if (tid < s2) r1[tid] = fminf(r1[tid], r1[tid + s2]);
    __syncthreads();
  }
  float inv = 1.0f / (r1[0] + EPSF);
  __syncthreads();
  float sw = 0.f, mw = 0.f;
  #pragma unroll
  for (int t = 0; t < 16; ++t){
    float wv = expf((1.0f - v[t] * inv) * 2.0f);
    sw += wv; mw = fmaxf(mw, wv);
  }
  r1[tid] = sw; r2[tid] = mw; __syncthreads();
  for (int s2 = 128; s2 > 0; s2 >>= 1){
    if (tid < s2){ r1[tid] += r1[tid + s2]; r2[tid] = fmaxf(r2[tid], r2[tid + s2]); }
    __syncthreads();
  }
  if (tid == 0) logcx[i] = logf(r2[0] / r1[0]);
}

__global__ void k_final(const float* __restrict__ logcx, float* __restrict__ out){
  int tid = threadIdx.x;
  float s = 0.f;
  for (int t = tid; t < NS; t += 256) s += logcx[t];
  __shared__ float r[256];
  r[tid] = s; __syncthreads();
  for (int k = 128; k > 0; k >>= 1){
    if (tid < k) r[tid] += r[tid + k];
    __syncthreads();
  }
  if (tid == 0) out[0] = -(r[0] * (1.0f / 4096.0f));
}

extern "C" void kernel_launch(void* const* d_in, const int* in_sizes, int n_in,
                              void* d_out, int out_size, void* d_ws, size_t ws_size,
                              hipStream_t stream){
  (void)in_sizes; (void)n_in; (void)out_size; (void)ws_size;
  const float* tfeat = (const float*)d_in[0];
  const float* rfeat = (const float*)d_in[1];
  const float* mask  = (const float*)d_in[2];
  const float* tfld  = (const float*)d_in[3];
  const float* rfld  = (const float*)d_in[4];

  char* p = (char*)d_ws;
  auto take = [&](size_t bytes) -> char* {
    char* r = p; p += (bytes + 255) & ~(size_t)255; return r;
  };
  int*   idx    = (int*)  take(4 * NS * sizeof(int));
  int*   H      = (int*)  take(7056 * sizeof(int));
  int*   cntT   = (int*)  take(9 * sizeof(int));
  int*   cntR   = (int*)  take(9 * sizeof(int));
  int*   bktT   = (int*)  take(9 * 4096 * sizeof(int));
  int*   bktR   = (int*)  take(9 * 4096 * sizeof(int));
  float* ymean3 = (float*)take(128 * 3 * 49 * sizeof(float));
  float* nsq    = (float*)take(2 * NS * sizeof(float));
  float* rn     = (float*)take(2 * NS * sizeof(float));
  float* ntp    = (float*)take(NS * sizeof(float));
  float* nrp    = (float*)take(NS * sizeof(float));
  float* TP     = (float*)take((size_t)49 * NS * sizeof(float));
  float* RP     = (float*)take((size_t)49 * NS * sizeof(float));
  u8*    Xt     = (u8*)   take((size_t)NS * KP);
  u8*    Xr     = (u8*)   take((size_t)NS * KP);
  float* D      = (float*)take((size_t)NS * NS * sizeof(float));
  float* lcx    = (float*)take(NS * sizeof(float));

  hipMemsetAsync(nsq, 0, 2 * NS * sizeof(float), stream);
  hipMemsetAsync(H, 0, 7056 * sizeof(int), stream);
  hipMemsetAsync(cntT, 0, 9 * sizeof(int), stream);
  hipMemsetAsync(cntR, 0, 9 * sizeof(int), stream);
  k_idx<<<32, 256, 0, stream>>>(tfld, rfld, idx, H, cntT, bktT, cntR, bktR);
  k_mean2<<<dim3(128, 3), 256, 0, stream>>>(rfeat, H, ymean3);
  k_gather<<<dim3(128, 9), 256, 0, stream>>>(tfeat, idx,          idx + NS,     cntT, bktT, ymean3, Xt, nsq);
  k_gather<<<dim3(128, 9), 256, 0, stream>>>(rfeat, idx + 2 * NS, idx + 3 * NS, cntR, bktR, ymean3, Xr, nsq + NS);
  k_rnorm<<<32, 256, 0, stream>>>(nsq, rn);
  k_maskg<<<16, 256, 0, stream>>>(mask, idx,          idx + NS,     TP, ntp);
  k_maskg<<<16, 256, 0, stream>>>(mask, idx + 2 * NS, idx + 3 * NS, RP, nrp);
  k_dprog<<<dim3(32, 32), 256, 0, stream>>>(TP, RP, ntp, nrp, D);
  k_gemm<<<1024, 256, 0, stream>>>(Xt, Xr, rn, rn + NS, D);
  k_rowred<<<4096, 256, 0, stream>>>(D, lcx);
  k_final<<<1, 256, 0, stream>>>(lcx, (float*)d_out);
}

// Round 7
// 478.223 us; speedup vs baseline: 1.3700x; 1.0258x over previous
//
#include <hip/hip_runtime.h>
#include <hip/hip_bf16.h>

typedef unsigned short u16;
typedef unsigned char  u8;
typedef unsigned int   u32;
typedef long long      i64;
using f32x4 = __attribute__((ext_vector_type(4))) float;
using i32x8 = __attribute__((ext_vector_type(8))) int;

#define EPSF 2.220446049250313e-16f
#define NS 4096      // samples
#define KP 6656      // padded K bytes: 128 ch * 52 (49 real + 3 zero-pad)
#define FSCALE 32.0f

#define GPTR(p) ((const __attribute__((address_space(1))) void*)(p))
#define LPTR(p) ((__attribute__((address_space(3))) void*)(p))

union frag8 { i32x8 v; i64 q[4]; };

// ---------------- prep: indices, buckets, histogram, mask patches ----------------
// idx layout: [ix_t | iy_t | ix_r | iy_r], 4096 each.
__global__ __launch_bounds__(256) void k_prep(const float* __restrict__ tfld,
                                              const float* __restrict__ rfld,
                                              const float* __restrict__ mask,
                                              int* __restrict__ idx, int* __restrict__ H,
                                              int* __restrict__ cntT, int* __restrict__ bktT,
                                              int* __restrict__ cntR, int* __restrict__ bktR,
                                              float* __restrict__ TP, float* __restrict__ RP,
                                              float* __restrict__ ntp, float* __restrict__ nrp){
  int t = blockIdx.x * 256 + threadIdx.x;
  if (t >= 2 * NS) return;
  const float* f = (t < NS) ? tfld : rfld;
  int s = t & (NS - 1);
  int base = (t < NS) ? 0 : 2 * NS;
  float gx = (f[2*s]   + 1.0f) * 0.5f * 83.0f;
  float gy = (f[2*s+1] + 1.0f) * 0.5f * 83.0f;
  int ix = (int)fminf(fmaxf(rintf(gx), 0.0f), 83.0f);
  int iy = (int)fminf(fmaxf(rintf(gy), 0.0f), 83.0f);
  idx[base + s]      = ix;
  idx[base + NS + s] = iy;
  int tile = (iy / 28) * 3 + (ix / 28);
  if (t < NS){
    int e = atomicAdd(&cntT[tile], 1);
    bktT[tile * 4096 + e] = s;
  } else {
    atomicAdd(&H[iy * 84 + ix], 1);
    int e = atomicAdd(&cntR[tile], 1);
    bktR[tile * 4096 + e] = s;
  }
  // mask patch gather (k-major) + squared norm
  float* P  = (t < NS) ? TP  : RP;
  float* np = (t < NS) ? ntp : nrp;
  int bx = ix * 3, by = iy * 3;
  float ss = 0.f;
  #pragma unroll
  for (int ki = 0; ki < 7; ++ki){
    #pragma unroll
    for (int kj = 0; kj < 7; ++kj){
      float v = mask[(by + ki) * 256 + (bx + kj)];
      P[(ki * 7 + kj) * NS + s] = v;
      ss += v * v;
    }
  }
  np[s] = ss;
}

// ---------------- per-channel mean, split into 3 row-bands ----------------
__global__ __launch_bounds__(256) void k_mean2(const float* __restrict__ refer,
                                               const int* __restrict__ H,
                                               float* __restrict__ ymean3){
  __shared__ int   Hs[28 * 84];
  __shared__ float part[4][49];
  int c = blockIdx.x, band = blockIdx.y;
  const float* plane = refer + ((size_t)c << 16);
  int ybase = band * 28;
  for (int p = threadIdx.x; p < 2352; p += 256) Hs[p] = H[ybase * 84 + p];
  __syncthreads();
  float acc[49];
  #pragma unroll
  for (int k = 0; k < 49; ++k) acc[k] = 0.f;
  for (int e = threadIdx.x; e < 2352; e += 256){
    int w = Hs[e];
    if (w){
      int y0 = ybase + e / 84, x0 = e % 84;
      float fw = (float)w;
      const float* pp = plane + (y0 * 3) * 256 + x0 * 3;
      #pragma unroll
      for (int ki = 0; ki < 7; ++ki)
        #pragma unroll
        for (int kj = 0; kj < 7; ++kj)
          acc[ki * 7 + kj] += fw * pp[ki * 256 + kj];
    }
  }
  int lane = threadIdx.x & 63, wid = threadIdx.x >> 6;
  #pragma unroll
  for (int k = 0; k < 49; ++k){
    float v = acc[k];
    #pragma unroll
    for (int o = 32; o > 0; o >>= 1) v += __shfl_down(v, o);
    if (lane == 0) part[wid][k] = v;
  }
  __syncthreads();
  for (int k = threadIdx.x; k < 49; k += 256)
    ymean3[(c * 3 + band) * 49 + k] =
      (part[0][k] + part[1][k] + part[2][k] + part[3][k]) * (1.0f / 4096.0f);
}

// ---------------- bucketed gather -> fp8 X (z dim selects target/refer) ----------------
// X row s: 1664 dwords; logical dword w stored at slot w ^ (2*(s&1)).
// channel c owns logical dwords c*13 .. c*13+12 (49 fp8 bytes * FSCALE + 3 zero pad)
__global__ __launch_bounds__(256) void k_gather(const float* __restrict__ tfeat,
                                                const float* __restrict__ rfeat,
                                                const int* __restrict__ idx,
                                                const int* __restrict__ cntT,
                                                const int* __restrict__ bktT,
                                                const int* __restrict__ cntR,
                                                const int* __restrict__ bktR,
                                                const float* __restrict__ ymean3,
                                                u8* __restrict__ Xt, u8* __restrict__ Xr,
                                                float* __restrict__ nsq){
  __shared__ float R[88 * 92];
  __shared__ float ms[49];
  int sel = blockIdx.z;
  const float* feat = sel ? rfeat : tfeat;
  const int* ixv = idx + sel * 2 * NS;
  const int* iyv = ixv + NS;
  const int* cnt = sel ? cntR : cntT;
  const int* bkt = sel ? bktR : bktT;
  u8* X = sel ? Xr : Xt;
  float* nq = nsq + sel * NS;

  int c = blockIdx.x;      // 0..127
  int t = blockIdx.y;      // 0..8
  int ty = t / 3, tx = t % 3;
  const float* src = feat + ((size_t)c << 16) + (ty * 84) * 256 + tx * 84;
  for (int e = threadIdx.x; e < 88 * 22; e += 256){
    int r = e / 22, q = e % 22;
    *(f32x4*)&R[r * 92 + q * 4] = *(const f32x4*)(src + r * 256 + q * 4);
  }
  for (int k = threadIdx.x; k < 49; k += 256)
    ms[k] = ymean3[(c*3)*49 + k] + ymean3[(c*3+1)*49 + k] + ymean3[(c*3+2)*49 + k];
  __syncthreads();
  int n = cnt[t];
  const int* list = bkt + t * 4096;
  for (int e = threadIdx.x; e < n; e += 256){
    int s = list[e];
    int ly = iyv[s] * 3 - ty * 84;
    int lx = ixv[s] * 3 - tx * 84;
    u32* xr = (u32*)(X + (size_t)s * KP);
    int wbase = c * 13;
    int sw = (s & 1) << 1;
    float ss = 0.f;
    #pragma unroll
    for (int d = 0; d < 12; ++d){
      float v0 = R[(ly + (4*d+0)/7) * 92 + lx + (4*d+0)%7] - ms[4*d+0];
      float v1 = R[(ly + (4*d+1)/7) * 92 + lx + (4*d+1)%7] - ms[4*d+1];
      float v2 = R[(ly + (4*d+2)/7) * 92 + lx + (4*d+2)%7] - ms[4*d+2];
      float v3 = R[(ly + (4*d+3)/7) * 92 + lx + (4*d+3)%7] - ms[4*d+3];
      ss += v0*v0 + v1*v1 + v2*v2 + v3*v3;
      u32 dw = (u32)__builtin_amdgcn_cvt_pk_fp8_f32(v0 * FSCALE, v1 * FSCALE, 0, false);
      dw = (u32)__builtin_amdgcn_cvt_pk_fp8_f32(v2 * FSCALE, v3 * FSCALE, (int)dw, true);
      xr[(wbase + d) ^ sw] = dw;
    }
    float v = R[(ly + 6) * 92 + lx + 6] - ms[48];
    ss += v * v;
    xr[(wbase + 12) ^ sw] = (u32)__builtin_amdgcn_cvt_pk_fp8_f32(v * FSCALE, 0.0f, 0, false);
    atomicAdd(&nq[s], ss);
  }
}

// ---------------- d_prog: D[i][j] = (10/49)*max(0, nrp[j]+ntp[i]-2*tp_j.rp_i) ----------------
__global__ __launch_bounds__(256) void k_dprog(const float* __restrict__ TP,
                                               const float* __restrict__ RP,
                                               const float* __restrict__ ntp,
                                               const float* __restrict__ nrp,
                                               float* __restrict__ D){
  __shared__ float Ts[49][128];
  __shared__ float Rs[49][128];
  int j0 = blockIdx.x * 128, i0 = blockIdx.y * 128;
  for (int e = threadIdx.x; e < 49 * 128; e += 256){
    int k = e >> 7, s = e & 127;
    Ts[k][s] = TP[k * NS + j0 + s];
    Rs[k][s] = RP[k * NS + i0 + s];
  }
  __syncthreads();
  int tx = threadIdx.x & 15, ty = threadIdx.x >> 4;
  float acc[8][8] = {};
  for (int k = 0; k < 49; ++k){
    float ra[8], rb[8];
    #pragma unroll
    for (int a = 0; a < 8; ++a) ra[a] = Rs[k][ty * 8 + a];
    #pragma unroll
    for (int b = 0; b < 8; ++b) rb[b] = Ts[k][tx * 8 + b];
    #pragma unroll
    for (int a = 0; a < 8; ++a)
      #pragma unroll
      for (int b = 0; b < 8; ++b) acc[a][b] += ra[a] * rb[b];
  }
  #pragma unroll
  for (int a = 0; a < 8; ++a){
    int i = i0 + ty * 8 + a;
    float ni = ntp[i];
    #pragma unroll
    for (int b = 0; b < 8; ++b){
      int j = j0 + tx * 8 + b;
      float v = nrp[j] + ni - 2.0f * acc[a][b];
      D[(size_t)i * NS + j] = fmaxf(v, 0.0f) * (10.0f / 49.0f);
    }
  }
}

// ---------------- main GEMM (MX fp8, K=128 MFMA, scales=1.0) ----------------
// 128x128 tile, BK=128 bytes, 52 K-iters. LDS: logical 8-B block b of row r at
// block b^(r&15) (conflict-free frag reads). Staging XOR (r>>1)&7 on 16-B chunks;
// X pre-permuted (dword w -> w^(2*(r&1))) completes the swizzle.
// NOTE: no min-waves launch bound — (256,4) forced a 64/64 AGPR/VGPR split and
// scratch-spilled the K-loop (WRITE_SIZE 820 MB, r5). Unconstrained = 124 VGPR,
// 4 blocks/CU, no spill (r6-verified).
__global__ __launch_bounds__(256) void k_gemm(const u8* __restrict__ Xt,
                                              const u8* __restrict__ Xr,
                                              const float* __restrict__ nsq,
                                              float* __restrict__ D){
  __shared__ u8 As[128 * 128];
  __shared__ u8 Bs[128 * 128];
  const int tid  = threadIdx.x;
  const int lane = tid & 63;
  const int w    = tid >> 6;
  const int wm   = w >> 1, wn = w & 1;
  const int b    = blockIdx.x;
  const int xcd  = b & 7, kb = b >> 3;
  const int i0 = ((xcd & 3) * 8 + (kb & 7)) * 128;
  const int j0 = ((xcd >> 2) * 16 + (kb >> 3)) * 128;

  // staging: wave w stages rows [w*32, w*32+32), 4 issues of 8 rows
  const int srow = lane >> 3;              // 0..7
  const int cs   = lane & 7;               // LDS 16-B chunk
  const int g0   = cs ^ (srow >> 1);       // global chunk, even issues
  const int g1   = g0 ^ 4;                 // odd issues
  const u8* gae = Xt + (size_t)(i0 + w * 32 + srow) * KP + g0 * 16;
  const u8* gao = Xt + (size_t)(i0 + w * 32 + srow) * KP + g1 * 16;
  const u8* gbe = Xr + (size_t)(j0 + w * 32 + srow) * KP + g0 * 16;
  const u8* gbo = Xr + (size_t)(j0 + w * 32 + srow) * KP + g1 * 16;
  u8* la = As + (w * 32) * 128;
  u8* lb = Bs + (w * 32) * 128;

  const int kg   = lane >> 4;              // 0..3 (K-group; also C/D row group)
  const int mrow = lane & 15;
  int offA[4], offB[4];
  #pragma unroll
  for (int j = 0; j < 4; ++j){
    offA[j] = (wm * 64 + mrow) * 128 + (((kg * 4 + j) ^ mrow) * 8);
    offB[j] = (wn * 64 + mrow) * 128 + (((kg * 4 + j) ^ mrow) * 8);
  }

  f32x4 acc[4][4] = {};

  for (int kt = 0; kt < 52; ++kt){        // 52 * 128 = 6656
    #pragma unroll
    for (int ii = 0; ii < 4; ++ii){
      const u8* pa = (ii & 1) ? gao : gae;
      const u8* pb = (ii & 1) ? gbo : gbe;
      __builtin_amdgcn_global_load_lds(GPTR(pa + ii * 8 * KP), LPTR(la + ii * 1024), 16, 0, 0);
      __builtin_amdgcn_global_load_lds(GPTR(pb + ii * 8 * KP), LPTR(lb + ii * 1024), 16, 0, 0);
    }
    gae += 128; gao += 128; gbe += 128; gbo += 128;
    __syncthreads();

    frag8 bf[4];
    #pragma unroll
    for (int t = 0; t < 4; ++t)
      #pragma unroll
      for (int j = 0; j < 4; ++j)
        bf[t].q[j] = *(const i64*)(Bs + offB[j] + t * 2048);
    #pragma unroll
    for (int a = 0; a < 4; ++a){
      frag8 af;
      #pragma unroll
      for (int j = 0; j < 4; ++j)
        af.q[j] = *(const i64*)(As + offA[j] + a * 2048);
      #pragma unroll
      for (int bq = 0; bq < 4; ++bq)
        acc[a][bq] = __builtin_amdgcn_mfma_scale_f32_16x16x128_f8f6f4(
            af.v, bf[bq].v, acc[a][bq], 0, 0, 0, 127, 0, 127);
    }
    __syncthreads();
  }

  // epilogue: C/D layout col=lane&15 (j), row=kg*4+reg (i).
  // reciprocal norms computed inline from nsq (1/FSCALE folds the fp8 scaling)
  const float* nsqt = nsq;
  const float* nsqr = nsq + NS;
  float rit[4][4];
  #pragma unroll
  for (int a = 0; a < 4; ++a)
    #pragma unroll
    for (int r = 0; r < 4; ++r){
      int i = i0 + wm * 64 + a * 16 + kg * 4 + r;
      rit[a][r] = (1.0f / FSCALE) / (sqrtf(nsqt[i]) + EPSF);
    }
  #pragma unroll
  for (int bq = 0; bq < 4; ++bq){
    int j = j0 + wn * 64 + bq * 16 + mrow;
    float rj = (1.0f / FSCALE) / (sqrtf(nsqr[j]) + EPSF);
    #pragma unroll
    for (int a = 0; a < 4; ++a){
      #pragma unroll
      for (int r = 0; r < 4; ++r){
        int i = i0 + wm * 64 + a * 16 + kg * 4 + r;
        float sim  = acc[a][bq][r] * rit[a][r] * rj;
        float dcos = fmaxf((1.0f - sim) * 0.5f, 0.0f);
        D[(size_t)i * NS + j] += dcos;
      }
    }
  }
}

// ---------------- per-row: min -> w=exp(2(1-d/dmin)) -> atomic -mean log(CX) ----------------
__global__ __launch_bounds__(256) void k_rowred(const float* __restrict__ D,
                                                float* __restrict__ out){
  int i = blockIdx.x, tid = threadIdx.x;
  const float* row = D + (size_t)i * NS;
  float v[16];
  float mn = 3.4e38f;
  #pragma unroll
  for (int t = 0; t < 16; ++t){ v[t] = row[tid + t * 256]; mn = fminf(mn, v[t]); }
  __shared__ float r1[256], r2[256];
  r1[tid] = mn; __syncthreads();
  for (int s2 = 128; s2 > 0; s2 >>= 1){
    if (tid < s2) r1[tid] = fminf(r1[tid], r1[tid + s2]);
    __syncthreads();
  }
  float inv = 1.0f / (r1[0] + EPSF);
  __syncthreads();
  float sw = 0.f, mw = 0.f;
  #pragma unroll
  for (int t = 0; t < 16; ++t){
    float wv = expf((1.0f - v[t] * inv) * 2.0f);
    sw += wv; mw = fmaxf(mw, wv);
  }
  r1[tid] = sw; r2[tid] = mw; __syncthreads();
  for (int s2 = 128; s2 > 0; s2 >>= 1){
    if (tid < s2){ r1[tid] += r1[tid + s2]; r2[tid] = fmaxf(r2[tid], r2[tid + s2]); }
    __syncthreads();
  }
  if (tid == 0) atomicAdd(out, logf(r2[0] / r1[0]) * (-1.0f / 4096.0f));
}

extern "C" void kernel_launch(void* const* d_in, const int* in_sizes, int n_in,
                              void* d_out, int out_size, void* d_ws, size_t ws_size,
                              hipStream_t stream){
  (void)in_sizes; (void)n_in; (void)out_size; (void)ws_size;
  const float* tfeat = (const float*)d_in[0];
  const float* rfeat = (const float*)d_in[1];
  const float* mask  = (const float*)d_in[2];
  const float* tfld  = (const float*)d_in[3];
  const float* rfld  = (const float*)d_in[4];

  char* p = (char*)d_ws;
  auto take = [&](size_t bytes) -> char* {
    char* r = p; p += (bytes + 255) & ~(size_t)255; return r;
  };
  int*   idx    = (int*)  take(4 * NS * sizeof(int));
  // ---- contiguous zero-region: H, cntT, cntR, nsq (single memset) ----
  int*   H      = (int*)  take(7056 * sizeof(int));
  int*   cntT   = (int*)  take(9 * sizeof(int));
  int*   cntR   = (int*)  take(9 * sizeof(int));
  float* nsq    = (float*)take(2 * NS * sizeof(float));
  size_t zspan  = (size_t)((char*)(nsq + 2 * NS) - (char*)H);
  // -------------------------------------------------------------------
  int*   bktT   = (int*)  take(9 * 4096 * sizeof(int));
  int*   bktR   = (int*)  take(9 * 4096 * sizeof(int));
  float* ymean3 = (float*)take(128 * 3 * 49 * sizeof(float));
  float* ntp    = (float*)take(NS * sizeof(float));
  float* nrp    = (float*)take(NS * sizeof(float));
  float* TP     = (float*)take((size_t)49 * NS * sizeof(float));
  float* RP     = (float*)take((size_t)49 * NS * sizeof(float));
  u8*    Xt     = (u8*)   take((size_t)NS * KP);
  u8*    Xr     = (u8*)   take((size_t)NS * KP);
  float* D      = (float*)take((size_t)NS * NS * sizeof(float));

  hipMemsetAsync(H, 0, zspan, stream);
  hipMemsetAsync(d_out, 0, sizeof(float), stream);
  k_prep<<<32, 256, 0, stream>>>(tfld, rfld, mask, idx, H, cntT, bktT, cntR, bktR,
                                 TP, RP, ntp, nrp);
  k_mean2<<<dim3(128, 3), 256, 0, stream>>>(rfeat, H, ymean3);
  k_gather<<<dim3(128, 9, 2), 256, 0, stream>>>(tfeat, rfeat, idx, cntT, bktT,
                                                cntR, bktR, ymean3, Xt, Xr, nsq);
  k_dprog<<<dim3(32, 32), 256, 0, stream>>>(TP, RP, ntp, nrp, D);
  k_gemm<<<1024, 256, 0, stream>>>(Xt, Xr, nsq, D);
  k_rowred<<<4096, 256, 0, stream>>>(D, (float*)d_out);
}

// Round 8
// 456.125 us; speedup vs baseline: 1.4364x; 1.0484x over previous
//
#include <hip/hip_runtime.h>
#include <hip/hip_bf16.h>

typedef unsigned short u16;
typedef unsigned char  u8;
typedef unsigned int   u32;
typedef unsigned long long u64;
typedef long long      i64;
using f32x4 = __attribute__((ext_vector_type(4))) float;
using i32x8 = __attribute__((ext_vector_type(8))) int;

#define EPSF 2.220446049250313e-16f
#define NS 4096      // samples
#define KP 6656      // padded K bytes: 128 ch * 52 (49 real + 3 zero-pad)
#define FSCALE 32.0f

#define GPTR(p) ((const __attribute__((address_space(1))) void*)(p))
#define LPTR(p) ((__attribute__((address_space(3))) void*)(p))

union frag8 { i32x8 v; i64 q[4]; };

__device__ __forceinline__ float bf2f(u16 u){
  union { unsigned i; float f; } x; x.i = ((unsigned)u) << 16; return x.f;
}
__device__ __forceinline__ u16 f2bf(float f){
  union { float f; unsigned u; } x; x.f = f;
  unsigned r = (x.u + 0x7FFFu + ((x.u >> 16) & 1u)) >> 16;   // RNE
  return (u16)r;
}

// ---------------- prep: indices, buckets (wave-aggregated), histogram, mask patches ----------------
// idx layout: [ix_t | iy_t | ix_r | iy_r], 4096 each. Exactly 8192 threads.
__global__ __launch_bounds__(256) void k_prep(const float* __restrict__ tfld,
                                              const float* __restrict__ rfld,
                                              const float* __restrict__ mask,
                                              int* __restrict__ idx, int* __restrict__ H,
                                              int* __restrict__ cntT, int* __restrict__ bktT,
                                              int* __restrict__ cntR, int* __restrict__ bktR,
                                              u16* __restrict__ TP, u16* __restrict__ RP,
                                              float* __restrict__ ntp, float* __restrict__ nrp){
  int t = blockIdx.x * 256 + threadIdx.x;        // 0..8191, no stragglers
  int lane = threadIdx.x & 63;
  const float* f = (t < NS) ? tfld : rfld;
  int s = t & (NS - 1);
  int base = (t < NS) ? 0 : 2 * NS;
  float gx = (f[2*s]   + 1.0f) * 0.5f * 83.0f;
  float gy = (f[2*s+1] + 1.0f) * 0.5f * 83.0f;
  int ix = (int)fminf(fmaxf(rintf(gx), 0.0f), 83.0f);
  int iy = (int)fminf(fmaxf(rintf(gy), 0.0f), 83.0f);
  idx[base + s]      = ix;
  idx[base + NS + s] = iy;
  if (t >= NS) atomicAdd(&H[iy * 84 + ix], 1);

  // wave-aggregated bucket insert: one global atomic per wave per tile
  int tile = (iy / 28) * 3 + (ix / 28);
  int* cnt = (t < NS) ? cntT : cntR;             // wave-uniform (blocks don't straddle halves)
  int* bkt = (t < NS) ? bktT : bktR;
  u64 lt = (lane == 63) ? ~0ull >> 1 : ((1ull << (lane + 1)) - 1) >> 1;  // lanes < me
  for (int tt = 0; tt < 9; ++tt){
    u64 m = __ballot(tile == tt);
    if (m){
      int leader = __builtin_ctzll(m);
      int cbase = 0;
      if (lane == leader) cbase = atomicAdd(&cnt[tt], (int)__popcll(m));
      cbase = __shfl(cbase, leader);
      if (tile == tt) bkt[tt * 4096 + cbase + (int)__popcll(m & lt)] = s;
    }
  }

  // mask patch gather (k-major, bf16) + exact fp32 squared norm
  u16*  P  = (t < NS) ? TP  : RP;
  float* np = (t < NS) ? ntp : nrp;
  int bx = ix * 3, by = iy * 3;
  float ss = 0.f;
  #pragma unroll
  for (int ki = 0; ki < 7; ++ki){
    #pragma unroll
    for (int kj = 0; kj < 7; ++kj){
      float v = mask[(by + ki) * 256 + (bx + kj)];
      P[(ki * 7 + kj) * NS + s] = f2bf(v);
      ss += v * v;
    }
  }
  np[s] = ss;
}

// ---------------- per-channel mean, split into 3 row-bands ----------------
__global__ __launch_bounds__(256) void k_mean2(const float* __restrict__ refer,
                                               const int* __restrict__ H,
                                               float* __restrict__ ymean3){
  __shared__ int   Hs[28 * 84];
  __shared__ float part[4][49];
  int c = blockIdx.x, band = blockIdx.y;
  const float* plane = refer + ((size_t)c << 16);
  int ybase = band * 28;
  for (int p = threadIdx.x; p < 2352; p += 256) Hs[p] = H[ybase * 84 + p];
  __syncthreads();
  float acc[49];
  #pragma unroll
  for (int k = 0; k < 49; ++k) acc[k] = 0.f;
  for (int e = threadIdx.x; e < 2352; e += 256){
    int w = Hs[e];
    if (w){
      int y0 = ybase + e / 84, x0 = e % 84;
      float fw = (float)w;
      const float* pp = plane + (y0 * 3) * 256 + x0 * 3;
      #pragma unroll
      for (int ki = 0; ki < 7; ++ki)
        #pragma unroll
        for (int kj = 0; kj < 7; ++kj)
          acc[ki * 7 + kj] += fw * pp[ki * 256 + kj];
    }
  }
  int lane = threadIdx.x & 63, wid = threadIdx.x >> 6;
  #pragma unroll
  for (int k = 0; k < 49; ++k){
    float v = acc[k];
    #pragma unroll
    for (int o = 32; o > 0; o >>= 1) v += __shfl_down(v, o);
    if (lane == 0) part[wid][k] = v;
  }
  __syncthreads();
  for (int k = threadIdx.x; k < 49; k += 256)
    ymean3[(c * 3 + band) * 49 + k] =
      (part[0][k] + part[1][k] + part[2][k] + part[3][k]) * (1.0f / 4096.0f);
}

// ---------------- bucketed gather -> fp8 X (z dim selects target/refer) ----------------
__global__ __launch_bounds__(256) void k_gather(const float* __restrict__ tfeat,
                                                const float* __restrict__ rfeat,
                                                const int* __restrict__ idx,
                                                const int* __restrict__ cntT,
                                                const int* __restrict__ bktT,
                                                const int* __restrict__ cntR,
                                                const int* __restrict__ bktR,
                                                const float* __restrict__ ymean3,
                                                u8* __restrict__ Xt, u8* __restrict__ Xr,
                                                float* __restrict__ nsq){
  __shared__ float R[88 * 92];
  __shared__ float ms[49];
  int sel = blockIdx.z;
  const float* feat = sel ? rfeat : tfeat;
  const int* ixv = idx + sel * 2 * NS;
  const int* iyv = ixv + NS;
  const int* cnt = sel ? cntR : cntT;
  const int* bkt = sel ? bktR : bktT;
  u8* X = sel ? Xr : Xt;
  float* nq = nsq + sel * NS;

  int c = blockIdx.x;      // 0..127
  int t = blockIdx.y;      // 0..8
  int ty = t / 3, tx = t % 3;
  const float* src = feat + ((size_t)c << 16) + (ty * 84) * 256 + tx * 84;
  for (int e = threadIdx.x; e < 88 * 22; e += 256){
    int r = e / 22, q = e % 22;
    *(f32x4*)&R[r * 92 + q * 4] = *(const f32x4*)(src + r * 256 + q * 4);
  }
  for (int k = threadIdx.x; k < 49; k += 256)
    ms[k] = ymean3[(c*3)*49 + k] + ymean3[(c*3+1)*49 + k] + ymean3[(c*3+2)*49 + k];
  __syncthreads();
  int n = cnt[t];
  const int* list = bkt + t * 4096;
  for (int e = threadIdx.x; e < n; e += 256){
    int s = list[e];
    int ly = iyv[s] * 3 - ty * 84;
    int lx = ixv[s] * 3 - tx * 84;
    u32* xr = (u32*)(X + (size_t)s * KP);
    int wbase = c * 13;
    int sw = (s & 1) << 1;
    float ss = 0.f;
    #pragma unroll
    for (int d = 0; d < 12; ++d){
      float v0 = R[(ly + (4*d+0)/7) * 92 + lx + (4*d+0)%7] - ms[4*d+0];
      float v1 = R[(ly + (4*d+1)/7) * 92 + lx + (4*d+1)%7] - ms[4*d+1];
      float v2 = R[(ly + (4*d+2)/7) * 92 + lx + (4*d+2)%7] - ms[4*d+2];
      float v3 = R[(ly + (4*d+3)/7) * 92 + lx + (4*d+3)%7] - ms[4*d+3];
      ss += v0*v0 + v1*v1 + v2*v2 + v3*v3;
      u32 dw = (u32)__builtin_amdgcn_cvt_pk_fp8_f32(v0 * FSCALE, v1 * FSCALE, 0, false);
      dw = (u32)__builtin_amdgcn_cvt_pk_fp8_f32(v2 * FSCALE, v3 * FSCALE, (int)dw, true);
      xr[(wbase + d) ^ sw] = dw;
    }
    float v = R[(ly + 6) * 92 + lx + 6] - ms[48];
    ss += v * v;
    xr[(wbase + 12) ^ sw] = (u32)__builtin_amdgcn_cvt_pk_fp8_f32(v * FSCALE, 0.0f, 0, false);
    atomicAdd(&nq[s], ss);
  }
}

// ---------------- reciprocal norms (1/FSCALE folded in) ----------------
__global__ void k_rnorm(const float* __restrict__ nsq, float* __restrict__ rn){
  int i = blockIdx.x * 256 + threadIdx.x;
  if (i < 2 * NS) rn[i] = (1.0f / FSCALE) / (sqrtf(nsq[i]) + EPSF);
}

// ---------------- main GEMM (MX fp8, K=128 MFMA, scales=1.0) + fused d_prog epilogue ----------------
// 128x128 tile, BK=128 bytes, 52 K-iters. LDS: logical 8-B block b of row r at
// block b^(r&15) (conflict-free frag reads). Staging XOR (r>>1)&7 on 16-B chunks;
// X pre-permuted (dword w -> w^(2*(r&1))) completes the swizzle.
// Epilogue: stages TP/RP (bf16) into the freed As/Bs, computes d_prog dot (K=49)
// in VALU, writes D = dcos + dprog once (no RMW, no separate dprog kernel).
// NOTE: no min-waves launch bound (r5: (256,4) => 64/64 RF split => 820 MB spill).
__global__ __launch_bounds__(256) void k_gemm(const u8* __restrict__ Xt,
                                              const u8* __restrict__ Xr,
                                              const u16* __restrict__ TP,
                                              const u16* __restrict__ RP,
                                              const float* __restrict__ ntp,
                                              const float* __restrict__ nrp,
                                              const float* __restrict__ rn,
                                              float* __restrict__ D){
  __shared__ u8 As[128 * 128];
  __shared__ u8 Bs[128 * 128];
  const int tid  = threadIdx.x;
  const int lane = tid & 63;
  const int w    = tid >> 6;
  const int wm   = w >> 1, wn = w & 1;
  const int b    = blockIdx.x;
  const int xcd  = b & 7, kb = b >> 3;
  const int i0 = ((xcd & 3) * 8 + (kb & 7)) * 128;
  const int j0 = ((xcd >> 2) * 16 + (kb >> 3)) * 128;

  const int srow = lane >> 3;              // 0..7
  const int cs   = lane & 7;               // LDS 16-B chunk
  const int g0   = cs ^ (srow >> 1);       // global chunk, even issues
  const int g1   = g0 ^ 4;                 // odd issues
  const u8* gae = Xt + (size_t)(i0 + w * 32 + srow) * KP + g0 * 16;
  const u8* gao = Xt + (size_t)(i0 + w * 32 + srow) * KP + g1 * 16;
  const u8* gbe = Xr + (size_t)(j0 + w * 32 + srow) * KP + g0 * 16;
  const u8* gbo = Xr + (size_t)(j0 + w * 32 + srow) * KP + g1 * 16;
  u8* la = As + (w * 32) * 128;
  u8* lb = Bs + (w * 32) * 128;

  const int kg   = lane >> 4;              // 0..3 (K-group; also C/D row group)
  const int mrow = lane & 15;
  int offA[4], offB[4];
  #pragma unroll
  for (int j = 0; j < 4; ++j){
    offA[j] = (wm * 64 + mrow) * 128 + (((kg * 4 + j) ^ mrow) * 8);
    offB[j] = (wn * 64 + mrow) * 128 + (((kg * 4 + j) ^ mrow) * 8);
  }

  f32x4 acc[4][4] = {};

  for (int kt = 0; kt < 52; ++kt){        // 52 * 128 = 6656
    #pragma unroll
    for (int ii = 0; ii < 4; ++ii){
      const u8* pa = (ii & 1) ? gao : gae;
      const u8* pb = (ii & 1) ? gbo : gbe;
      __builtin_amdgcn_global_load_lds(GPTR(pa + ii * 8 * KP), LPTR(la + ii * 1024), 16, 0, 0);
      __builtin_amdgcn_global_load_lds(GPTR(pb + ii * 8 * KP), LPTR(lb + ii * 1024), 16, 0, 0);
    }
    gae += 128; gao += 128; gbe += 128; gbo += 128;
    __syncthreads();

    frag8 bf[4];
    #pragma unroll
    for (int t = 0; t < 4; ++t)
      #pragma unroll
      for (int j = 0; j < 4; ++j)
        bf[t].q[j] = *(const i64*)(Bs + offB[j] + t * 2048);
    #pragma unroll
    for (int a = 0; a < 4; ++a){
      frag8 af;
      #pragma unroll
      for (int j = 0; j < 4; ++j)
        af.q[j] = *(const i64*)(As + offA[j] + a * 2048);
      #pragma unroll
      for (int bq = 0; bq < 4; ++bq)
        acc[a][bq] = __builtin_amdgcn_mfma_scale_f32_16x16x128_f8f6f4(
            af.v, bf[bq].v, acc[a][bq], 0, 0, 0, 127, 0, 127);
    }
    __syncthreads();
  }

  // ---- stage TP/RP tiles (bf16) into freed LDS ----
  u16* Tsh = (u16*)As;   // [49][128] over j-range
  u16* Rsh = (u16*)Bs;   // [49][128] over i-range
  for (int e = tid; e < 49 * 128; e += 256){
    int k = e >> 7, col = e & 127;
    Tsh[e] = TP[k * NS + j0 + col];
    Rsh[e] = RP[k * NS + i0 + col];
  }
  __syncthreads();

  // ---- epilogue: C/D col=lane&15 (j), row=kg*4+reg (i) ----
  float rjv[4], nrpv[4];
  #pragma unroll
  for (int bq = 0; bq < 4; ++bq){
    int j = j0 + wn * 64 + bq * 16 + mrow;
    rjv[bq]  = rn[NS + j];
    nrpv[bq] = nrp[j];
  }
  #pragma unroll
  for (int a = 0; a < 4; ++a){
    float dp[4][4] = {};   // [r][bq]
    for (int k = 0; k < 49; ++k){
      float rpv[4], tpv[4];
      #pragma unroll
      for (int r = 0; r < 4; ++r)
        rpv[r] = bf2f(Rsh[k * 128 + wm * 64 + a * 16 + kg * 4 + r]);
      #pragma unroll
      for (int bq = 0; bq < 4; ++bq)
        tpv[bq] = bf2f(Tsh[k * 128 + wn * 64 + bq * 16 + mrow]);
      #pragma unroll
      for (int r = 0; r < 4; ++r)
        #pragma unroll
        for (int bq = 0; bq < 4; ++bq)
          dp[r][bq] += rpv[r] * tpv[bq];
    }
    #pragma unroll
    for (int r = 0; r < 4; ++r){
      int i = i0 + wm * 64 + a * 16 + kg * 4 + r;
      float ni = ntp[i];
      float ri = rn[i];
      #pragma unroll
      for (int bq = 0; bq < 4; ++bq){
        int j = j0 + wn * 64 + bq * 16 + mrow;
        float dprog = fmaxf(nrpv[bq] + ni - 2.0f * dp[r][bq], 0.0f) * (10.0f / 49.0f);
        float sim   = acc[a][bq][r] * ri * rjv[bq];
        float dcos  = fmaxf((1.0f - sim) * 0.5f, 0.0f);
        D[(size_t)i * NS + j] = dcos + dprog;
      }
    }
  }
}

// ---------------- per-row: min -> w=exp(2(1-d/dmin)) -> atomic -mean log(CX) ----------------
__global__ __launch_bounds__(256) void k_rowred(const float* __restrict__ D,
                                                float* __restrict__ out){
  int i = blockIdx.x, tid = threadIdx.x;
  const f32x4* row4 = (const f32x4*)(D + (size_t)i * NS);
  f32x4 v[4];
  float mn = 3.4e38f;
  #pragma unroll
  for (int t = 0; t < 4; ++t){
    v[t] = row4[tid + t * 256];
    #pragma unroll
    for (int q = 0; q < 4; ++q) mn = fminf(mn, v[t][q]);
  }
  __shared__ float r1[256], r2[256];
  r1[tid] = mn; __syncthreads();
  for (int s2 = 128; s2 > 0; s2 >>= 1){
    if (tid < s2) r1[tid] = fminf(r1[tid], r1[tid + s2]);
    __syncthreads();
  }
  float inv = 1.0f / (r1[0] + EPSF);
  __syncthreads();
  float sw = 0.f, mw = 0.f;
  #pragma unroll
  for (int t = 0; t < 4; ++t)
    #pragma unroll
    for (int q = 0; q < 4; ++q){
      float wv = expf((1.0f - v[t][q] * inv) * 2.0f);
      sw += wv; mw = fmaxf(mw, wv);
    }
  r1[tid] = sw; r2[tid] = mw; __syncthreads();
  for (int s2 = 128; s2 > 0; s2 >>= 1){
    if (tid < s2){ r1[tid] += r1[tid + s2]; r2[tid] = fmaxf(r2[tid], r2[tid + s2]); }
    __syncthreads();
  }
  if (tid == 0) atomicAdd(out, logf(r2[0] / r1[0]) * (-1.0f / 4096.0f));
}

extern "C" void kernel_launch(void* const* d_in, const int* in_sizes, int n_in,
                              void* d_out, int out_size, void* d_ws, size_t ws_size,
                              hipStream_t stream){
  (void)in_sizes; (void)n_in; (void)out_size; (void)ws_size;
  const float* tfeat = (const float*)d_in[0];
  const float* rfeat = (const float*)d_in[1];
  const float* mask  = (const float*)d_in[2];
  const float* tfld  = (const float*)d_in[3];
  const float* rfld  = (const float*)d_in[4];

  char* p = (char*)d_ws;
  auto take = [&](size_t bytes) -> char* {
    char* r = p; p += (bytes + 255) & ~(size_t)255; return r;
  };
  int*   idx    = (int*)  take(4 * NS * sizeof(int));
  // ---- contiguous zero-region: H, cntT, cntR, nsq (single memset) ----
  int*   H      = (int*)  take(7056 * sizeof(int));
  int*   cntT   = (int*)  take(9 * sizeof(int));
  int*   cntR   = (int*)  take(9 * sizeof(int));
  float* nsq    = (float*)take(2 * NS * sizeof(float));
  size_t zspan  = (size_t)((char*)(nsq + 2 * NS) - (char*)H);
  // -------------------------------------------------------------------
  int*   bktT   = (int*)  take(9 * 4096 * sizeof(int));
  int*   bktR   = (int*)  take(9 * 4096 * sizeof(int));
  float* ymean3 = (float*)take(128 * 3 * 49 * sizeof(float));
  float* rn     = (float*)take(2 * NS * sizeof(float));
  float* ntp    = (float*)take(NS * sizeof(float));
  float* nrp    = (float*)take(NS * sizeof(float));
  u16*   TP     = (u16*)  take((size_t)49 * NS * sizeof(u16));
  u16*   RP     = (u16*)  take((size_t)49 * NS * sizeof(u16));
  u8*    Xt     = (u8*)   take((size_t)NS * KP);
  u8*    Xr     = (u8*)   take((size_t)NS * KP);
  float* D      = (float*)take((size_t)NS * NS * sizeof(float));

  hipMemsetAsync(H, 0, zspan, stream);
  hipMemsetAsync(d_out, 0, sizeof(float), stream);
  k_prep<<<32, 256, 0, stream>>>(tfld, rfld, mask, idx, H, cntT, bktT, cntR, bktR,
                                 TP, RP, ntp, nrp);
  k_mean2<<<dim3(128, 3), 256, 0, stream>>>(rfeat, H, ymean3);
  k_gather<<<dim3(128, 9, 2), 256, 0, stream>>>(tfeat, rfeat, idx, cntT, bktT,
                                                cntR, bktR, ymean3, Xt, Xr, nsq);
  k_rnorm<<<32, 256, 0, stream>>>(nsq, rn);
  k_gemm<<<1024, 256, 0, stream>>>(Xt, Xr, TP, RP, ntp, nrp, rn, D);
  k_rowred<<<4096, 256, 0, stream>>>(D, (float*)d_out);
}